// Round 10
// baseline (236.157 us; speedup 1.0000x reference)
//
#include <hip/hip_runtime.h>
#include <hip/hip_bf16.h>

#define F0 512
#define F1 128
#define F2 40

#define NRP 12800   // nodes per histogram partition
#define G_SL 64     // edge slices

typedef __attribute__((ext_vector_type(8))) short bf16x8;
typedef __attribute__((ext_vector_type(4))) float f32x4;

__device__ inline ushort f2bf(float f) {
    union { float f; uint u; } v; v.f = f;
    uint u = v.u;
    uint r = u + 0x7fffu + ((u >> 16) & 1u);   // RNE
    return (ushort)(r >> 16);
}

#define CVT2(dst, a, b) { __hip_bfloat162 _t2 = __float22bfloat162_rn(make_float2(a, b)); __builtin_memcpy(&dst, &_t2, 4); }

// ---------------- pass 1: per-slice histograms + fused W1 & x preconvert ----------------
// grid = P * G_SL = 256 blocks of 1024 threads. The x->bf16 stream (153MB of BW work)
// overlaps the latency-bound LDS-atomic histogram phase.
__global__ __launch_bounds__(1024)
void hist_kernel(const int* __restrict__ src, const int* __restrict__ dst,
                 ushort* __restrict__ Gsrc, ushort* __restrict__ Gdst,
                 const float* __restrict__ W1, ushort* __restrict__ Wt,
                 const float* __restrict__ x, ushort* __restrict__ xb, int n, int E) {
    // fused W1 -> bf16 transpose: first 64 blocks cover 64*1024 = 65536 = F0*F1 elems
    if (blockIdx.x < (F0 * F1) / 1024) {
        int idx = blockIdx.x * 1024 + threadIdx.x;
        int k = idx >> 7, nn = idx & 127;
        Wt[nn * F0 + k] = f2bf(W1[idx]);
    }
    // fused x -> bf16 (row-major preserved): grid-stride, 8 floats / step
    {
        const int total = n * (F0 / 8);
        const int stride = gridDim.x * 1024;
        for (int i = blockIdx.x * 1024 + threadIdx.x; i < total; i += stride) {
            float4 p0 = *reinterpret_cast<const float4*>(x + (size_t)i * 8);
            float4 p1 = *reinterpret_cast<const float4*>(x + (size_t)i * 8 + 4);
            uint h0, h1, h2, h3;
            CVT2(h0, p0.x, p0.y); CVT2(h1, p0.z, p0.w);
            CVT2(h2, p1.x, p1.y); CVT2(h3, p1.z, p1.w);
            *reinterpret_cast<uint4*>(xb + (size_t)i * 8) = make_uint4(h0, h1, h2, h3);
        }
    }
    __shared__ uint cs[NRP / 2];
    __shared__ uint cd[NRP / 2];
    const int p = blockIdx.x / G_SL;
    const int g = blockIdx.x % G_SL;
    const int base = p * NRP;
    for (int i = threadIdx.x; i < NRP / 2; i += 1024) { cs[i] = 0; cd[i] = 0; }
    __syncthreads();
    const int Epg = (E + G_SL - 1) / G_SL;
    const int e0 = g * Epg;
    const int e1 = min(E, e0 + Epg);
    for (int i = e0 + (int)threadIdx.x; i < e1; i += 1024) {
        int s = src[i], d = dst[i];
        unsigned so = (unsigned)(s - base);
        unsigned dd = (unsigned)(d - base);
        if (so < (unsigned)NRP) atomicAdd(&cs[so >> 1], 1u << ((so & 1) * 16));
        if (dd < (unsigned)NRP) atomicAdd(&cd[dd >> 1], 1u << ((dd & 1) * 16));
    }
    __syncthreads();
    const int lim = min(NRP, n - base);
    for (int i = threadIdx.x; i < lim; i += 1024) {
        uint pcs = cs[i >> 1], pcd = cd[i >> 1];
        int sh = (i & 1) * 16;
        Gsrc[(size_t)g * n + base + i] = (ushort)((pcs >> sh) & 0xffffu);
        Gdst[(size_t)g * n + base + i] = (ushort)((pcd >> sh) & 0xffffu);
    }
}

// ---------------- pass 2: degree sums + norms + per-256-block inclusive scan ----------------
__global__ __launch_bounds__(256)
void scanA_kernel(const ushort* __restrict__ Gsrc, const ushort* __restrict__ Gdst,
                  float* __restrict__ norm_src, float* __restrict__ norm_dst,
                  int* __restrict__ row_off, int* __restrict__ bsum, int n) {
    __shared__ int sm[256];
    int i = blockIdx.x * 256 + threadIdx.x;
    int s = 0, d = 0;
    if (i < n) {
#pragma unroll
        for (int g = 0; g < G_SL; g++) {
            s += Gsrc[(size_t)g * n + i];
            d += Gdst[(size_t)g * n + i];
        }
        norm_src[i] = s > 0 ? rsqrtf((float)s) : 0.f;
        norm_dst[i] = d > 0 ? rsqrtf((float)d) : 0.f;
    }
    sm[threadIdx.x] = (i < n) ? d : 0;
    __syncthreads();
    for (int off = 1; off < 256; off <<= 1) {
        int t = (threadIdx.x >= (unsigned)off) ? sm[threadIdx.x - off] : 0;
        __syncthreads();
        sm[threadIdx.x] += t;
        __syncthreads();
    }
    if (i < n) row_off[i + 1] = sm[threadIdx.x];   // raw: in-block inclusive
    if (threadIdx.x == 255) bsum[blockIdx.x] = sm[255];
}

// ---------------- pass 3: finalize row_off (global exclusive) + per-slice start offsets ----------------
__global__ __launch_bounds__(256)
void finalize_kernel(int* __restrict__ row_off, const int* __restrict__ bsum,
                     const ushort* __restrict__ Gdst, int* __restrict__ Goff, int n) {
    __shared__ int sm[256];
    const int b = blockIdx.x;
    const int t = threadIdx.x;
    sm[t] = (t < b) ? bsum[t] : 0;
    __syncthreads();
#pragma unroll
    for (int off = 128; off > 0; off >>= 1) {
        if (t < off) sm[t] += sm[t + off];
        __syncthreads();
    }
    const int excl = sm[0];
    const int v = b * 256 + t;
    if (v >= n) return;
    int raw = row_off[v];                       // each index touched only by its own thread
    int start = excl + ((t == 0) ? 0 : raw);
    if (v == n - 1) {
        int rawn = row_off[n];
        row_off[n] = excl + rawn;
    }
    row_off[v] = start;
    int run = start;
#pragma unroll
    for (int g = 0; g < G_SL; g++) {
        size_t idx = (size_t)g * n + v;
        Goff[idx] = run;
        run += Gdst[idx];
    }
}

// ---------------- edge placement (counting sort; int LDS cursors seeded with global offsets) ----------------
__global__ __launch_bounds__(1024)
void place_kernel(const int* __restrict__ src, const int* __restrict__ dst,
                  const int* __restrict__ Goff, int* __restrict__ edge_src, int n, int E) {
    __shared__ int cur[NRP];   // 51.2KB
    const int p = blockIdx.x / G_SL;
    const int g = blockIdx.x % G_SL;
    const int base = p * NRP;
    const int lim = min(NRP, n - base);
    for (int i = threadIdx.x; i < lim; i += 1024)
        cur[i] = Goff[(size_t)g * n + base + i];
    __syncthreads();
    const int Epg = (E + G_SL - 1) / G_SL;
    const int e0 = g * Epg;
    const int e1 = min(E, e0 + Epg);
    for (int i = e0 + (int)threadIdx.x; i < e1; i += 1024) {
        int d = dst[i];
        unsigned dd = (unsigned)(d - base);
        if (dd < (unsigned)lim) {
            int pos = atomicAdd(&cur[dd], 1);
            edge_src[pos] = src[i];
        }
    }
}

// ---------------- GEMM1 v2 (MFMA bf16, NO LDS / NO barriers): h1g = (xb @ W1) * norm_src ----------------
// Wave owns 16 rows x all 128 cols. xb row-major IS the A-fragment layout (lane=row l15,
// k-chunk lq*8): all 16 K-tiles of A loaded upfront (256B/lane in flight -> high MLP).
// B (bf16 Wt, 128KB, L2-hot) read per-iter, 8 frags. Waves run barrier-free.
#define BM 64
__global__ __launch_bounds__(256)
void gemm1_mfma(const ushort* __restrict__ xb, const ushort* __restrict__ Wt,
                const float* __restrict__ norm_src, ushort* __restrict__ h1g, int n) {
    const int tid = threadIdx.x;
    const int lane = tid & 63;
    const int w = tid >> 6;
    const int l15 = lane & 15;
    const int lq = lane >> 4;
    const int rbase = blockIdx.x * BM + w * 16;

    const int arow = rbase + l15;
    const ushort* xrow = xb + (size_t)(arow < n ? arow : 0) * F0 + lq * 8;

    // whole-row A prefetch: 16 x bf16x8 (64 VGPR), all loads issued before any use
    bf16x8 a[16];
#pragma unroll
    for (int kt = 0; kt < 16; kt++)
        a[kt] = *reinterpret_cast<const bf16x8*>(xrow + kt * 32);

    const ushort* bp = Wt + (size_t)l15 * F0 + lq * 8;
    f32x4 acc[8] = {};

#pragma unroll
    for (int kt = 0; kt < 16; kt++) {
        bf16x8 b[8];
#pragma unroll
        for (int ni = 0; ni < 8; ni++)
            b[ni] = *reinterpret_cast<const bf16x8*>(bp + (size_t)ni * 16 * F0 + kt * 32);
#pragma unroll
        for (int ni = 0; ni < 8; ni++)
            acc[ni] = __builtin_amdgcn_mfma_f32_16x16x32_bf16(a[kt], b[ni], acc[ni], 0, 0, 0);
    }

    // epilogue: C layout col=lane&15, row=4*(lane>>4)+reg; store bf16
#pragma unroll
    for (int r = 0; r < 4; r++) {
        int orow = rbase + lq * 4 + r;
        if (orow < n) {
            float ns = norm_src[orow];
#pragma unroll
            for (int ni = 0; ni < 8; ni++) {
                h1g[(size_t)orow * F1 + ni * 16 + l15] = f2bf(acc[ni][r] * ns);
            }
        }
    }
}

// ---------------- Agg1: h1(bf16) = relu(segsum(h1g[src]) * norm_dst + b1), one wave per node ----------------
__global__ __launch_bounds__(256)
void agg1_kernel(const ushort* __restrict__ h1g, const int* __restrict__ row_off,
                 const int* __restrict__ edge_src, const float* __restrict__ norm_dst,
                 const float* __restrict__ b1, ushort* __restrict__ h1, int n) {
    int wid = (blockIdx.x * blockDim.x + threadIdx.x) >> 6;
    int lane = threadIdx.x & 63;
    if (wid >= n) return;
    int beg = row_off[wid], end = row_off[wid + 1];
    float a0 = 0.f, a1 = 0.f;
    int e = beg;
    for (; e + 7 < end; e += 8) {
        int s[8];
#pragma unroll
        for (int j = 0; j < 8; j++) s[j] = edge_src[e + j];
        uint v[8];
#pragma unroll
        for (int j = 0; j < 8; j++)
            v[j] = *reinterpret_cast<const uint*>(&h1g[(size_t)s[j] * F1 + lane * 2]);
#pragma unroll
        for (int j = 0; j < 8; j++) {
            a0 += __uint_as_float(v[j] << 16);
            a1 += __uint_as_float(v[j] & 0xffff0000u);
        }
    }
    for (; e < end; ++e) {
        int s = edge_src[e];
        uint v = *reinterpret_cast<const uint*>(&h1g[(size_t)s * F1 + lane * 2]);
        a0 += __uint_as_float(v << 16);
        a1 += __uint_as_float(v & 0xffff0000u);
    }
    float nd = norm_dst[wid];
    float o0 = fmaxf(a0 * nd + b1[lane * 2 + 0], 0.f);
    float o1 = fmaxf(a1 * nd + b1[lane * 2 + 1], 0.f);
    __hip_bfloat162 p2 = __float22bfloat162_rn(make_float2(o0, o1));
    uint pu; __builtin_memcpy(&pu, &p2, 4);
    *reinterpret_cast<uint*>(&h1[(size_t)wid * F1 + lane * 2]) = pu;
}

// ---------------- GEMM2: h2g(bf16) = (h1 @ W2) * norm_src  [n x 128] @ [128 x 40] ----------------
__global__ __launch_bounds__(256)
void gemm2_kernel(const ushort* __restrict__ h1, const float* __restrict__ W2,
                  const float* __restrict__ norm_src, ushort* __restrict__ h2g, int n) {
    __shared__ __align__(16) float W2s[F1][F2];
    for (int i = threadIdx.x; i < F1 * F2; i += 256)
        W2s[i / F2][i % F2] = W2[i];
    __syncthreads();
    int node = blockIdx.x * 256 + threadIdx.x;
    if (node >= n) return;
    float nrm = norm_src[node];
    f32x4 acc4[10] = {};
    const ushort* row = &h1[(size_t)node * F1];
    for (int kc = 0; kc < 16; kc++) {
        uint4 u = *reinterpret_cast<const uint4*>(&row[kc * 8]);
        uint uu[4] = {u.x, u.y, u.z, u.w};
        float f[8];
#pragma unroll
        for (int i = 0; i < 4; i++) {
            f[2 * i + 0] = __uint_as_float(uu[i] << 16);
            f[2 * i + 1] = __uint_as_float(uu[i] & 0xffff0000u);
        }
#pragma unroll
        for (int j = 0; j < 8; j++) {
#pragma unroll
            for (int c4 = 0; c4 < 10; c4++) {
                f32x4 wv = *reinterpret_cast<const f32x4*>(&W2s[kc * 8 + j][c4 * 4]);
                acc4[c4] += f[j] * wv;
            }
        }
    }
    ushort* orow = &h2g[(size_t)node * F2];
#pragma unroll
    for (int c4 = 0; c4 < 10; c4++) {
        f32x4 o = acc4[c4] * nrm;
        __hip_bfloat162 pa = __float22bfloat162_rn(make_float2(o[0], o[1]));
        __hip_bfloat162 pb = __float22bfloat162_rn(make_float2(o[2], o[3]));
        uint2 pk;
        __builtin_memcpy(&pk.x, &pa, 4);
        __builtin_memcpy(&pk.y, &pb, 4);
        *reinterpret_cast<uint2*>(&orow[c4 * 4]) = pk;
    }
}

// ---------------- Agg2: out = segsum(h2g[src]) * norm_dst + b2, one wave per node ----------------
__global__ __launch_bounds__(256)
void agg2_kernel(const ushort* __restrict__ h2g, const int* __restrict__ row_off,
                 const int* __restrict__ edge_src, const float* __restrict__ norm_dst,
                 const float* __restrict__ b2, float* __restrict__ out, int n) {
    int wid = (blockIdx.x * blockDim.x + threadIdx.x) >> 6;
    int lane = threadIdx.x & 63;
    if (wid >= n) return;
    int beg = row_off[wid], end = row_off[wid + 1];
    float a0 = 0.f, a1 = 0.f;
    int e = beg;
    const bool act = lane < 20;
    for (; e + 7 < end; e += 8) {
        int s[8];
#pragma unroll
        for (int j = 0; j < 8; j++) s[j] = edge_src[e + j];
        if (act) {
            uint v[8];
#pragma unroll
            for (int j = 0; j < 8; j++)
                v[j] = *reinterpret_cast<const uint*>(&h2g[(size_t)s[j] * F2 + lane * 2]);
#pragma unroll
            for (int j = 0; j < 8; j++) {
                a0 += __uint_as_float(v[j] << 16);
                a1 += __uint_as_float(v[j] & 0xffff0000u);
            }
        }
    }
    for (; e < end; ++e) {
        int s = edge_src[e];
        if (act) {
            uint v = *reinterpret_cast<const uint*>(&h2g[(size_t)s * F2 + lane * 2]);
            a0 += __uint_as_float(v << 16);
            a1 += __uint_as_float(v & 0xffff0000u);
        }
    }
    if (act) {
        float nd = norm_dst[wid];
        float o0 = a0 * nd + b2[lane * 2 + 0];
        float o1 = a1 * nd + b2[lane * 2 + 1];
        *reinterpret_cast<float2*>(&out[(size_t)wid * F2 + lane * 2]) = make_float2(o0, o1);
    }
}

extern "C" void kernel_launch(void* const* d_in, const int* in_sizes, int n_in,
                              void* d_out, int out_size, void* d_ws, size_t ws_size,
                              hipStream_t stream) {
    const float* x  = (const float*)d_in[0];
    const float* W1 = (const float*)d_in[1];
    const float* b1 = (const float*)d_in[2];
    const float* W2 = (const float*)d_in[3];
    const float* b2 = (const float*)d_in[4];
    const int* src  = (const int*)d_in[5];
    const int* dst  = (const int*)d_in[6];
    float* out = (float*)d_out;

    const int n = in_sizes[0] / F0;
    const int E = in_sizes[5];
    const int nb = (n + 255) / 256;
    const int P = (n + NRP - 1) / NRP;

    char* ws = (char*)d_ws;
    auto alloc = [&](size_t bytes) -> char* {
        char* p = ws;
        ws += (bytes + 255) & ~(size_t)255;
        return p;
    };
    int* row_off   = (int*)alloc((size_t)(n + 1) * 4);
    int* bsum      = (int*)alloc(256 * 4);
    int* edge_srcs = (int*)alloc((size_t)E * 4);
    float* norm_src_d = (float*)alloc((size_t)n * 4);
    float* norm_dst_d = (float*)alloc((size_t)n * 4);
    ushort* W1t = (ushort*)alloc((size_t)F1 * F0 * 2);
    ushort* xb  = (ushort*)alloc((size_t)n * F0 * 2);   // bf16 x (51.2MB)
    ushort* h1g = (ushort*)alloc((size_t)n * F1 * 2);   // bf16 (12.8MB)
    ushort* h1  = (ushort*)alloc((size_t)n * F1 * 2);   // bf16 (12.8MB)
    ushort* h2g = h1g;   // reuse after agg1: n*F2*2 <= n*F1*2

    // aliasing (dead before hosts go live):
    //   Gsrc/Gdst (ushort counts, 2 * G_SL*n*2 = 12.8MB) -> h1g region (live from gemm1)
    //   Goff      (int offsets,       G_SL*n*4 = 12.8MB) -> h1  region (live from agg1)
    ushort* Gsrc = (ushort*)h1g;
    ushort* Gdst = Gsrc + (size_t)G_SL * n;
    int* Goff = (int*)h1;

    hist_kernel<<<P * G_SL, 1024, 0, stream>>>(src, dst, Gsrc, Gdst, W1, W1t, x, xb, n, E);
    scanA_kernel<<<nb, 256, 0, stream>>>(Gsrc, Gdst, norm_src_d, norm_dst_d, row_off, bsum, n);
    finalize_kernel<<<nb, 256, 0, stream>>>(row_off, bsum, Gdst, Goff, n);
    place_kernel<<<P * G_SL, 1024, 0, stream>>>(src, dst, Goff, edge_srcs, n, E);
    gemm1_mfma<<<(n + BM - 1) / BM, 256, 0, stream>>>(xb, W1t, norm_src_d, h1g, n);
    agg1_kernel<<<(n + 3) / 4, 256, 0, stream>>>(h1g, row_off, edge_srcs, norm_dst_d, b1, h1, n);
    gemm2_kernel<<<(n + 255) / 256, 256, 0, stream>>>(h1, W2, norm_src_d, h2g, n);
    agg2_kernel<<<(n + 3) / 4, 256, 0, stream>>>(h2g, row_off, edge_srcs, norm_dst_d, b2, out, n);
}

// Round 11
// 181.872 us; speedup vs baseline: 1.2985x; 1.2985x over previous
//
#include <hip/hip_runtime.h>
#include <hip/hip_bf16.h>

#define F0 512
#define F1 128
#define F2 40

#define NRP 12800   // nodes per histogram partition
#define G_SL 64     // edge slices

typedef __attribute__((ext_vector_type(8))) short bf16x8;
typedef __attribute__((ext_vector_type(4))) float f32x4;

__device__ inline ushort f2bf(float f) {
    union { float f; uint u; } v; v.f = f;
    uint u = v.u;
    uint r = u + 0x7fffu + ((u >> 16) & 1u);   // RNE
    return (ushort)(r >> 16);
}

#define CVT2(dst, a, b) { __hip_bfloat162 _t2 = __float22bfloat162_rn(make_float2(a, b)); __builtin_memcpy(&dst, &_t2, 4); }

// ---------------- pass 1: per-slice histograms + fused W1 preconvert ----------------
__global__ __launch_bounds__(1024)
void hist_kernel(const int* __restrict__ src, const int* __restrict__ dst,
                 ushort* __restrict__ Gsrc, ushort* __restrict__ Gdst,
                 const float* __restrict__ W1, ushort* __restrict__ Wt, int n, int E) {
    if (blockIdx.x < (F0 * F1) / 1024) {
        int idx = blockIdx.x * 1024 + threadIdx.x;
        int k = idx >> 7, nn = idx & 127;
        Wt[nn * F0 + k] = f2bf(W1[idx]);
    }
    __shared__ uint cs[NRP / 2];
    __shared__ uint cd[NRP / 2];
    const int p = blockIdx.x / G_SL;
    const int g = blockIdx.x % G_SL;
    const int base = p * NRP;
    for (int i = threadIdx.x; i < NRP / 2; i += 1024) { cs[i] = 0; cd[i] = 0; }
    __syncthreads();
    const int Epg = (E + G_SL - 1) / G_SL;
    const int e0 = g * Epg;
    const int e1 = min(E, e0 + Epg);
    for (int i = e0 + (int)threadIdx.x; i < e1; i += 1024) {
        int s = src[i], d = dst[i];
        unsigned so = (unsigned)(s - base);
        unsigned dd = (unsigned)(d - base);
        if (so < (unsigned)NRP) atomicAdd(&cs[so >> 1], 1u << ((so & 1) * 16));
        if (dd < (unsigned)NRP) atomicAdd(&cd[dd >> 1], 1u << ((dd & 1) * 16));
    }
    __syncthreads();
    const int lim = min(NRP, n - base);
    for (int i = threadIdx.x; i < lim; i += 1024) {
        uint pcs = cs[i >> 1], pcd = cd[i >> 1];
        int sh = (i & 1) * 16;
        Gsrc[(size_t)g * n + base + i] = (ushort)((pcs >> sh) & 0xffffu);
        Gdst[(size_t)g * n + base + i] = (ushort)((pcd >> sh) & 0xffffu);
    }
}

// ---------------- pass 2: degree sums + norms + per-256-block inclusive scan ----------------
__global__ __launch_bounds__(256)
void scanA_kernel(const ushort* __restrict__ Gsrc, const ushort* __restrict__ Gdst,
                  float* __restrict__ norm_src, float* __restrict__ norm_dst,
                  int* __restrict__ row_off, int* __restrict__ bsum, int n) {
    __shared__ int sm[256];
    int i = blockIdx.x * 256 + threadIdx.x;
    int s = 0, d = 0;
    if (i < n) {
#pragma unroll
        for (int g = 0; g < G_SL; g++) {
            s += Gsrc[(size_t)g * n + i];
            d += Gdst[(size_t)g * n + i];
        }
        norm_src[i] = s > 0 ? rsqrtf((float)s) : 0.f;
        norm_dst[i] = d > 0 ? rsqrtf((float)d) : 0.f;
    }
    sm[threadIdx.x] = (i < n) ? d : 0;
    __syncthreads();
    for (int off = 1; off < 256; off <<= 1) {
        int t = (threadIdx.x >= (unsigned)off) ? sm[threadIdx.x - off] : 0;
        __syncthreads();
        sm[threadIdx.x] += t;
        __syncthreads();
    }
    if (i < n) row_off[i + 1] = sm[threadIdx.x];   // raw: in-block inclusive
    if (threadIdx.x == 255) bsum[blockIdx.x] = sm[255];
}

// ---------------- pass 3: finalize row_off (global exclusive) + per-slice start offsets ----------------
__global__ __launch_bounds__(256)
void finalize_kernel(int* __restrict__ row_off, const int* __restrict__ bsum,
                     const ushort* __restrict__ Gdst, int* __restrict__ Goff, int n) {
    __shared__ int sm[256];
    const int b = blockIdx.x;
    const int t = threadIdx.x;
    sm[t] = (t < b) ? bsum[t] : 0;
    __syncthreads();
#pragma unroll
    for (int off = 128; off > 0; off >>= 1) {
        if (t < off) sm[t] += sm[t + off];
        __syncthreads();
    }
    const int excl = sm[0];
    const int v = b * 256 + t;
    if (v >= n) return;
    int raw = row_off[v];
    int start = excl + ((t == 0) ? 0 : raw);
    if (v == n - 1) {
        int rawn = row_off[n];
        row_off[n] = excl + rawn;
    }
    row_off[v] = start;
    int run = start;
#pragma unroll
    for (int g = 0; g < G_SL; g++) {
        size_t idx = (size_t)g * n + v;
        Goff[idx] = run;
        run += Gdst[idx];
    }
}

// ---------------- edge placement (counting sort; int LDS cursors seeded with global offsets) ----------------
__global__ __launch_bounds__(1024)
void place_kernel(const int* __restrict__ src, const int* __restrict__ dst,
                  const int* __restrict__ Goff, int* __restrict__ edge_src, int n, int E) {
    __shared__ int cur[NRP];   // 51.2KB
    const int p = blockIdx.x / G_SL;
    const int g = blockIdx.x % G_SL;
    const int base = p * NRP;
    const int lim = min(NRP, n - base);
    for (int i = threadIdx.x; i < lim; i += 1024)
        cur[i] = Goff[(size_t)g * n + base + i];
    __syncthreads();
    const int Epg = (E + G_SL - 1) / G_SL;
    const int e0 = g * Epg;
    const int e1 = min(E, e0 + Epg);
    for (int i = e0 + (int)threadIdx.x; i < e1; i += 1024) {
        int d = dst[i];
        unsigned dd = (unsigned)(d - base);
        if (dd < (unsigned)lim) {
            int pos = atomicAdd(&cur[dd], 1);
            edge_src[pos] = src[i];
        }
    }
}

// ---------------- GEMM1 v3 (MFMA bf16, 8 waves/block): h1g = (x @ W1) * norm_src ----------------
// BM=64, 512 threads = 8 waves; wave w owns cols [w*16, w*16+16) x all 64 rows (acc[4], 1 B-frag).
// A (f32 x) converted+staged once per block in LDS fragment-linear layout (ds_write_b64 at
// t*8B = conflict-free), double-buffered, ONE barrier/iter. B (bf16 Wt, L2-hot) prefetched 1 ahead.
// Concurrency: VGPR~60, LDS 8KB -> ~24-32 waves/CU (vs 12 before) = TLP hides x latency.
#define BM 64

#define LOADX(dst, k0) { dst = arok ? *reinterpret_cast<const float4*>(xptr + (k0)) : make_float4(0.f, 0.f, 0.f, 0.f); }

#define STAGE(buf, xv) {                                                        \
    uint _h0, _h1;                                                              \
    CVT2(_h0, xv.x, xv.y); CVT2(_h1, xv.z, xv.w);                               \
    *reinterpret_cast<uint2*>(&Al[buf][smi][sflane][shalf * 4]) = make_uint2(_h0, _h1); }

#define LOADB(k0, b) { b = *reinterpret_cast<const bf16x8*>(bp + (k0)); }

#define COMPUTE(buf, b) {                                                               \
    bf16x8 _a0 = *reinterpret_cast<const bf16x8*>(&Al[buf][0][lane][0]);                \
    bf16x8 _a1 = *reinterpret_cast<const bf16x8*>(&Al[buf][1][lane][0]);                \
    bf16x8 _a2 = *reinterpret_cast<const bf16x8*>(&Al[buf][2][lane][0]);                \
    bf16x8 _a3 = *reinterpret_cast<const bf16x8*>(&Al[buf][3][lane][0]);                \
    acc[0] = __builtin_amdgcn_mfma_f32_16x16x32_bf16(_a0, b, acc[0], 0, 0, 0);          \
    acc[1] = __builtin_amdgcn_mfma_f32_16x16x32_bf16(_a1, b, acc[1], 0, 0, 0);          \
    acc[2] = __builtin_amdgcn_mfma_f32_16x16x32_bf16(_a2, b, acc[2], 0, 0, 0);          \
    acc[3] = __builtin_amdgcn_mfma_f32_16x16x32_bf16(_a3, b, acc[3], 0, 0, 0); }

__global__ __launch_bounds__(512)
void gemm1_mfma(const float* __restrict__ x, const ushort* __restrict__ Wt,
                const float* __restrict__ norm_src, ushort* __restrict__ h1g, int n) {
    __shared__ __align__(16) ushort Al[2][4][64][8];   // [buf][mi][flane][8] = 8KB

    const int tid = threadIdx.x;
    const int lane = tid & 63;
    const int w = tid >> 6;            // 0..7: wave's 16-col group
    const int l15 = lane & 15;
    const int lq = lane >> 4;
    const int bm = blockIdx.x * BM;

    // A staging: thread t -> (smi = t>>7, sflane = (t>>1)&63, shalf = t&1), one float4
    const int smi = tid >> 7;
    const int sflane = (tid >> 1) & 63;
    const int shalf = tid & 1;
    const int srow = smi * 16 + (sflane & 15);
    const int skc = ((sflane >> 4) << 3) + shalf * 4;
    const int grow = bm + srow;
    const bool arok = grow < n;
    const float* xptr = x + (size_t)(arok ? grow : 0) * F0 + skc;

    // B: wave w covers cols w*16 .. w*16+15 (one 16x16 frag per k-tile)
    const ushort* bp = Wt + (size_t)(w * 16 + l15) * F0 + lq * 8;

    f32x4 acc[4] = {};
    float4 xnxt;
    bf16x8 bcur, bnxt;

    // prologue
    LOADX(xnxt, 0);
    LOADB(0, bcur);
    STAGE(0, xnxt);
    __syncthreads();

    for (int kt2 = 0; kt2 < 8; kt2++) {
        const int kb = kt2 * 2;
        // iter kb (buf 0)
        {
            LOADX(xnxt, (kb + 1) * 32);
            LOADB((kb + 1) * 32, bnxt);
            COMPUTE(0, bcur);
            STAGE(1, xnxt);
            bcur = bnxt;
            __syncthreads();
        }
        // iter kb+1 (buf 1)
        if (kb + 1 < 15) {
            LOADX(xnxt, (kb + 2) * 32);
            LOADB((kb + 2) * 32, bnxt);
            COMPUTE(1, bcur);
            STAGE(0, xnxt);
            bcur = bnxt;
            __syncthreads();
        } else {
            COMPUTE(1, bcur);
        }
    }

    // epilogue: C layout col=lane&15, row=4*(lane>>4)+reg; store bf16
#pragma unroll
    for (int mi = 0; mi < 4; mi++) {
        int rbase = bm + mi * 16 + lq * 4;
#pragma unroll
        for (int r = 0; r < 4; r++) {
            int row = rbase + r;
            if (row < n) {
                float ns = norm_src[row];
                h1g[(size_t)row * F1 + w * 16 + l15] = f2bf(acc[mi][r] * ns);
            }
        }
    }
}

// ---------------- Agg1: h1(bf16) = relu(segsum(h1g[src]) * norm_dst + b1), one wave per node ----------------
__global__ __launch_bounds__(256)
void agg1_kernel(const ushort* __restrict__ h1g, const int* __restrict__ row_off,
                 const int* __restrict__ edge_src, const float* __restrict__ norm_dst,
                 const float* __restrict__ b1, ushort* __restrict__ h1, int n) {
    int wid = (blockIdx.x * blockDim.x + threadIdx.x) >> 6;
    int lane = threadIdx.x & 63;
    if (wid >= n) return;
    int beg = row_off[wid], end = row_off[wid + 1];
    float a0 = 0.f, a1 = 0.f;
    int e = beg;
    for (; e + 7 < end; e += 8) {
        int s[8];
#pragma unroll
        for (int j = 0; j < 8; j++) s[j] = edge_src[e + j];
        uint v[8];
#pragma unroll
        for (int j = 0; j < 8; j++)
            v[j] = *reinterpret_cast<const uint*>(&h1g[(size_t)s[j] * F1 + lane * 2]);
#pragma unroll
        for (int j = 0; j < 8; j++) {
            a0 += __uint_as_float(v[j] << 16);
            a1 += __uint_as_float(v[j] & 0xffff0000u);
        }
    }
    for (; e < end; ++e) {
        int s = edge_src[e];
        uint v = *reinterpret_cast<const uint*>(&h1g[(size_t)s * F1 + lane * 2]);
        a0 += __uint_as_float(v << 16);
        a1 += __uint_as_float(v & 0xffff0000u);
    }
    float nd = norm_dst[wid];
    float o0 = fmaxf(a0 * nd + b1[lane * 2 + 0], 0.f);
    float o1 = fmaxf(a1 * nd + b1[lane * 2 + 1], 0.f);
    __hip_bfloat162 p2 = __float22bfloat162_rn(make_float2(o0, o1));
    uint pu; __builtin_memcpy(&pu, &p2, 4);
    *reinterpret_cast<uint*>(&h1[(size_t)wid * F1 + lane * 2]) = pu;
}

// ---------------- GEMM2: h2g(bf16) = (h1 @ W2) * norm_src  [n x 128] @ [128 x 40] ----------------
__global__ __launch_bounds__(256)
void gemm2_kernel(const ushort* __restrict__ h1, const float* __restrict__ W2,
                  const float* __restrict__ norm_src, ushort* __restrict__ h2g, int n) {
    __shared__ __align__(16) float W2s[F1][F2];
    for (int i = threadIdx.x; i < F1 * F2; i += 256)
        W2s[i / F2][i % F2] = W2[i];
    __syncthreads();
    int node = blockIdx.x * 256 + threadIdx.x;
    if (node >= n) return;
    float nrm = norm_src[node];
    f32x4 acc4[10] = {};
    const ushort* row = &h1[(size_t)node * F1];
    for (int kc = 0; kc < 16; kc++) {
        uint4 u = *reinterpret_cast<const uint4*>(&row[kc * 8]);
        uint uu[4] = {u.x, u.y, u.z, u.w};
        float f[8];
#pragma unroll
        for (int i = 0; i < 4; i++) {
            f[2 * i + 0] = __uint_as_float(uu[i] << 16);
            f[2 * i + 1] = __uint_as_float(uu[i] & 0xffff0000u);
        }
#pragma unroll
        for (int j = 0; j < 8; j++) {
#pragma unroll
            for (int c4 = 0; c4 < 10; c4++) {
                f32x4 wv = *reinterpret_cast<const f32x4*>(&W2s[kc * 8 + j][c4 * 4]);
                acc4[c4] += f[j] * wv;
            }
        }
    }
    ushort* orow = &h2g[(size_t)node * F2];
#pragma unroll
    for (int c4 = 0; c4 < 10; c4++) {
        f32x4 o = acc4[c4] * nrm;
        __hip_bfloat162 pa = __float22bfloat162_rn(make_float2(o[0], o[1]));
        __hip_bfloat162 pb = __float22bfloat162_rn(make_float2(o[2], o[3]));
        uint2 pk;
        __builtin_memcpy(&pk.x, &pa, 4);
        __builtin_memcpy(&pk.y, &pb, 4);
        *reinterpret_cast<uint2*>(&orow[c4 * 4]) = pk;
    }
}

// ---------------- Agg2: out = segsum(h2g[src]) * norm_dst + b2, one wave per node ----------------
__global__ __launch_bounds__(256)
void agg2_kernel(const ushort* __restrict__ h2g, const int* __restrict__ row_off,
                 const int* __restrict__ edge_src, const float* __restrict__ norm_dst,
                 const float* __restrict__ b2, float* __restrict__ out, int n) {
    int wid = (blockIdx.x * blockDim.x + threadIdx.x) >> 6;
    int lane = threadIdx.x & 63;
    if (wid >= n) return;
    int beg = row_off[wid], end = row_off[wid + 1];
    float a0 = 0.f, a1 = 0.f;
    int e = beg;
    const bool act = lane < 20;
    for (; e + 7 < end; e += 8) {
        int s[8];
#pragma unroll
        for (int j = 0; j < 8; j++) s[j] = edge_src[e + j];
        if (act) {
            uint v[8];
#pragma unroll
            for (int j = 0; j < 8; j++)
                v[j] = *reinterpret_cast<const uint*>(&h2g[(size_t)s[j] * F2 + lane * 2]);
#pragma unroll
            for (int j = 0; j < 8; j++) {
                a0 += __uint_as_float(v[j] << 16);
                a1 += __uint_as_float(v[j] & 0xffff0000u);
            }
        }
    }
    for (; e < end; ++e) {
        int s = edge_src[e];
        if (act) {
            uint v = *reinterpret_cast<const uint*>(&h2g[(size_t)s * F2 + lane * 2]);
            a0 += __uint_as_float(v << 16);
            a1 += __uint_as_float(v & 0xffff0000u);
        }
    }
    if (act) {
        float nd = norm_dst[wid];
        float o0 = a0 * nd + b2[lane * 2 + 0];
        float o1 = a1 * nd + b2[lane * 2 + 1];
        *reinterpret_cast<float2*>(&out[(size_t)wid * F2 + lane * 2]) = make_float2(o0, o1);
    }
}

extern "C" void kernel_launch(void* const* d_in, const int* in_sizes, int n_in,
                              void* d_out, int out_size, void* d_ws, size_t ws_size,
                              hipStream_t stream) {
    const float* x  = (const float*)d_in[0];
    const float* W1 = (const float*)d_in[1];
    const float* b1 = (const float*)d_in[2];
    const float* W2 = (const float*)d_in[3];
    const float* b2 = (const float*)d_in[4];
    const int* src  = (const int*)d_in[5];
    const int* dst  = (const int*)d_in[6];
    float* out = (float*)d_out;

    const int n = in_sizes[0] / F0;
    const int E = in_sizes[5];
    const int nb = (n + 255) / 256;
    const int P = (n + NRP - 1) / NRP;

    char* ws = (char*)d_ws;
    auto alloc = [&](size_t bytes) -> char* {
        char* p = ws;
        ws += (bytes + 255) & ~(size_t)255;
        return p;
    };
    int* row_off   = (int*)alloc((size_t)(n + 1) * 4);
    int* bsum      = (int*)alloc(256 * 4);
    int* edge_srcs = (int*)alloc((size_t)E * 4);
    float* norm_src_d = (float*)alloc((size_t)n * 4);
    float* norm_dst_d = (float*)alloc((size_t)n * 4);
    ushort* W1t = (ushort*)alloc((size_t)F1 * F0 * 2);
    ushort* h1g = (ushort*)alloc((size_t)n * F1 * 2);   // bf16 (12.8MB)
    ushort* h1  = (ushort*)alloc((size_t)n * F1 * 2);   // bf16 (12.8MB)
    ushort* h2g = h1g;   // reuse after agg1: n*F2*2 <= n*F1*2

    // aliasing (dead before hosts go live):
    //   Gsrc/Gdst (ushort counts, 2 * G_SL*n*2 = 12.8MB) -> h1g region (live from gemm1)
    //   Goff      (int offsets,       G_SL*n*4 = 12.8MB) -> h1  region (live from agg1)
    ushort* Gsrc = (ushort*)h1g;
    ushort* Gdst = Gsrc + (size_t)G_SL * n;
    int* Goff = (int*)h1;

    hist_kernel<<<P * G_SL, 1024, 0, stream>>>(src, dst, Gsrc, Gdst, W1, W1t, n, E);
    scanA_kernel<<<nb, 256, 0, stream>>>(Gsrc, Gdst, norm_src_d, norm_dst_d, row_off, bsum, n);
    finalize_kernel<<<nb, 256, 0, stream>>>(row_off, bsum, Gdst, Goff, n);
    place_kernel<<<P * G_SL, 1024, 0, stream>>>(src, dst, Goff, edge_srcs, n, E);
    gemm1_mfma<<<(n + BM - 1) / BM, 512, 0, stream>>>(x, W1t, norm_src_d, h1g, n);
    agg1_kernel<<<(n + 3) / 4, 256, 0, stream>>>(h1g, row_off, edge_srcs, norm_dst_d, b1, h1, n);
    gemm2_kernel<<<(n + 255) / 256, 256, 0, stream>>>(h1, W2, norm_src_d, h2g, n);
    agg2_kernel<<<(n + 3) / 4, 256, 0, stream>>>(h2g, row_off, edge_srcs, norm_dst_d, b2, out, n);
}